// Round 16
// baseline (596.109 us; speedup 1.0000x reference)
//
#include <hip/hip_runtime.h>
#include <hip/hip_bf16.h>

#define N_NODES 50000
#define N_EDGES 800000
#define F_IN 128
#define DIM 256
#define NUM_CLASSES 10
#define NUM_GRAPHS 256
#define NBKT ((N_NODES + 255) / 256)
#define BCAP 8192
#define NRT ((N_NODES + 127) / 128)

typedef short bf16x8 __attribute__((ext_vector_type(8)));
typedef float f32x4 __attribute__((ext_vector_type(4)));

__device__ __forceinline__ float bf2f(unsigned short u) {
    union { unsigned int u; float f; } c;
    c.u = ((unsigned int)u) << 16;
    return c.f;
}
__device__ __forceinline__ unsigned short f2bf(float f) {
    union { float f; unsigned int u; } c;
    c.f = f;
    unsigned int r = (c.u + 0x7fffu + ((c.u >> 16) & 1u)) >> 16;
    return (unsigned short)r;
}
__device__ __forceinline__ float u2f(unsigned int u) {
    union { unsigned int u; float f; } c;
    c.u = u;
    return c.f;
}
__device__ __forceinline__ unsigned int f2u(float f) {
    union { float f; unsigned int u; } c;
    c.f = f;
    return c.u;
}

__device__ __forceinline__ void gload16(const unsigned short* g, unsigned short* l) {
    __builtin_amdgcn_global_load_lds(
        (const __attribute__((address_space(1))) unsigned int*)(g),
        (__attribute__((address_space(3))) unsigned int*)(l), 16, 0, 0);
}

// ---------------- CSR build (bucket-level only) ----------------

__global__ void bucket_hist(const int* __restrict__ dst, int* __restrict__ bcnt, int E) {
    __shared__ int c[NBKT];
    int t = threadIdx.x;
    for (int i = t; i < NBKT; i += 256) c[i] = 0;
    __syncthreads();
    int ebase = blockIdx.x * 4096 + t;
#pragma unroll
    for (int i = 0; i < 16; ++i) {
        int e = ebase + i * 256;
        if (e < E) atomicAdd(&c[dst[e] >> 8], 1);
    }
    __syncthreads();
    for (int i = t; i < NBKT; i += 256)
        if (c[i]) atomicAdd(&bcnt[i], c[i]);
}

__global__ void scan_bkt(const int* __restrict__ bcnt, int* __restrict__ bbase,
                         int* __restrict__ gbase) {
    __shared__ int sd[256];
    int t = threadIdx.x;
    int v = (t < NBKT) ? bcnt[t] : 0;
    sd[t] = v;
    __syncthreads();
    for (int off = 1; off < 256; off <<= 1) {
        int u = (t >= off) ? sd[t - off] : 0;
        __syncthreads();
        sd[t] += u;
        __syncthreads();
    }
    if (t < NBKT) {
        int ex = sd[t] - v;
        bbase[t] = ex;
        gbase[t] = ex;
    }
    if (t == NBKT - 1) bbase[NBKT] = sd[t];
}

__global__ __launch_bounds__(256) void bucket_scatter(
    const int* __restrict__ src, const int* __restrict__ dst, const float* __restrict__ ew,
    int* __restrict__ gbase, uint2* __restrict__ edata2, int E) {
    __shared__ int cnt[NBKT];
    __shared__ int base_s[NBKT];
    int t = threadIdx.x;
    int ebase = blockIdx.x * 4096 + t;
    for (int i = t; i < NBKT; i += 256) cnt[i] = 0;
    __syncthreads();
#pragma unroll
    for (int i = 0; i < 16; ++i) {
        int e = ebase + i * 256;
        if (e < E) atomicAdd(&cnt[dst[e] >> 8], 1);
    }
    __syncthreads();
    for (int i = t; i < NBKT; i += 256) {
        int c = cnt[i];
        base_s[i] = c ? atomicAdd(&gbase[i], c) : 0;
        cnt[i] = 0;
    }
    __syncthreads();
#pragma unroll
    for (int i = 0; i < 16; ++i) {
        int e = ebase + i * 256;
        if (e < E) {
            int d = dst[e];
            int bkt = d >> 8;
            int r = atomicAdd(&cnt[bkt], 1);
            edata2[base_s[bkt] + r] =
                make_uint2((unsigned)src[e] | ((unsigned)(d & 255) << 16), f2u(ew[e]));
        }
    }
}

__global__ __launch_bounds__(256) void bucket_sort(
    const int* __restrict__ bbase, const uint2* __restrict__ edata2, uint2* __restrict__ edata,
    int* __restrict__ offs) {
    __shared__ uint2 stage[BCAP];
    __shared__ int cnt[256];
    __shared__ int sd[256];
    int b = blockIdx.x, t = threadIdx.x;
    int lo = bbase[b];
    int hi = bbase[b + 1];
    int ce = hi - lo;
    cnt[t] = 0;
    __syncthreads();
    for (int i = t; i < ce; i += 256) {
        uint2 e = edata2[lo + i];
        atomicAdd(&cnt[(e.x >> 16) & 255], 1);
    }
    __syncthreads();
    int myc = cnt[t];
    sd[t] = myc;
    __syncthreads();
    for (int off = 1; off < 256; off <<= 1) {
        int u = (t >= off) ? sd[t - off] : 0;
        __syncthreads();
        sd[t] += u;
        __syncthreads();
    }
    int ex = sd[t] - myc;
    __syncthreads();
    sd[t] = ex;
    cnt[t] = 0;
    int node = b * 256 + t;
    if (node < N_NODES) offs[node] = lo + ex;
    if (node == N_NODES - 1) offs[N_NODES] = lo + ex + myc;
    __syncthreads();
    if (ce <= BCAP) {
        for (int i = t; i < ce; i += 256) {
            uint2 e = edata2[lo + i];
            int dl = (e.x >> 16) & 255;
            int r = atomicAdd(&cnt[dl], 1);
            stage[sd[dl] + r] = make_uint2(e.x & 0xFFFFu, e.y);
        }
        __syncthreads();
        for (int i = t; i < ce; i += 256) edata[lo + i] = stage[i];
    } else {
        for (int i = t; i < ce; i += 256) {
            uint2 e = edata2[lo + i];
            int dl = (e.x >> 16) & 255;
            int r = atomicAdd(&cnt[dl], 1);
            edata[lo + sd[dl] + r] = make_uint2(e.x & 0xFFFFu, e.y);
        }
    }
}

// ---------------- dtype prep ----------------

__global__ void conv_x(const float* __restrict__ x, unsigned short* __restrict__ xb, int n4) {
    int i = blockIdx.x * blockDim.x + threadIdx.x;
    if (i >= n4) return;
    float4 v = ((const float4*)x)[i];
    ushort4 o;
    o.x = f2bf(v.x); o.y = f2bf(v.y); o.z = f2bf(v.z); o.w = f2bf(v.w);
    ((ushort4*)xb)[i] = o;
}

__global__ void pack_w(const float* __restrict__ Wr, const float* __restrict__ Wo,
                       unsigned short* __restrict__ Bt, int K) {
    int idx = blockIdx.x * blockDim.x + threadIdx.x;
    int total = 2 * K * DIM;
    if (idx >= total) return;
    int k = idx / DIM, c = idx % DIM;
    float v = (k < K) ? Wr[k * DIM + c] : Wo[(k - K) * DIM + c];
    Bt[(size_t)c * (2 * K) + k] = f2bf(v);
}

__global__ void pack_w4(const float* __restrict__ W2r, const float* __restrict__ W2o,
                        const float* __restrict__ W3r, const float* __restrict__ W3o,
                        const float* __restrict__ W4r, const float* __restrict__ W4o,
                        const float* __restrict__ W5r, const float* __restrict__ W5o,
                        unsigned short* __restrict__ B2, unsigned short* __restrict__ B3,
                        unsigned short* __restrict__ B4, unsigned short* __restrict__ B5) {
    int idx = blockIdx.x * blockDim.x + threadIdx.x;
    int total = 2 * DIM * DIM;
    if (idx >= total) return;
    int L = blockIdx.y;
    const float* Wr = (L == 0) ? W2r : (L == 1) ? W3r : (L == 2) ? W4r : W5r;
    const float* Wo = (L == 0) ? W2o : (L == 1) ? W3o : (L == 2) ? W4o : W5o;
    unsigned short* Bt = (L == 0) ? B2 : (L == 1) ? B3 : (L == 2) ? B4 : B5;
    int k = idx / DIM, c = idx % DIM;
    float v = (k < DIM) ? Wr[k * DIM + c] : Wo[(k - DIM) * DIM + c];
    Bt[(size_t)c * (2 * DIM) + k] = f2bf(v);
}

// ---------------- per-node aggregation ----------------
// 2 edges per wave (half-wave hf), 32 sub-lanes x 16B per row, 8-edge unroll.

template <int F>
__global__ void agg_bf16(const unsigned short* __restrict__ hsrc, const int* __restrict__ offs,
                         const uint2* __restrict__ edata, unsigned short* __restrict__ agg) {
    int node = blockIdx.x * (blockDim.x >> 6) + (threadIdx.x >> 6);
    if (node >= N_NODES) return;
    int lane = threadIdx.x & 63;
    int hf = lane >> 5;
    int sl = lane & 31;
    int s0 = offs[node], s1 = offs[node + 1];
    if (F == 256) {
        const unsigned short* hb = hsrc + sl * 8;
        float acc[8] = {0.f, 0.f, 0.f, 0.f, 0.f, 0.f, 0.f, 0.f};
        int p = s0;
        for (; p + 7 < s1; p += 8) {
            uint2 e0 = edata[p + hf];
            uint2 e1 = edata[p + 2 + hf];
            uint2 e2 = edata[p + 4 + hf];
            uint2 e3 = edata[p + 6 + hf];
            float w0 = u2f(e0.y), w1 = u2f(e1.y), w2 = u2f(e2.y), w3 = u2f(e3.y);
            uint4 r0 = *(const uint4*)(hb + (size_t)e0.x * 256);
            uint4 r1 = *(const uint4*)(hb + (size_t)e1.x * 256);
            uint4 r2 = *(const uint4*)(hb + (size_t)e2.x * 256);
            uint4 r3 = *(const uint4*)(hb + (size_t)e3.x * 256);
            acc[0] += w0 * bf2f((unsigned short)r0.x);
            acc[1] += w0 * bf2f((unsigned short)(r0.x >> 16));
            acc[2] += w0 * bf2f((unsigned short)r0.y);
            acc[3] += w0 * bf2f((unsigned short)(r0.y >> 16));
            acc[4] += w0 * bf2f((unsigned short)r0.z);
            acc[5] += w0 * bf2f((unsigned short)(r0.z >> 16));
            acc[6] += w0 * bf2f((unsigned short)r0.w);
            acc[7] += w0 * bf2f((unsigned short)(r0.w >> 16));
            acc[0] += w1 * bf2f((unsigned short)r1.x);
            acc[1] += w1 * bf2f((unsigned short)(r1.x >> 16));
            acc[2] += w1 * bf2f((unsigned short)r1.y);
            acc[3] += w1 * bf2f((unsigned short)(r1.y >> 16));
            acc[4] += w1 * bf2f((unsigned short)r1.z);
            acc[5] += w1 * bf2f((unsigned short)(r1.z >> 16));
            acc[6] += w1 * bf2f((unsigned short)r1.w);
            acc[7] += w1 * bf2f((unsigned short)(r1.w >> 16));
            acc[0] += w2 * bf2f((unsigned short)r2.x);
            acc[1] += w2 * bf2f((unsigned short)(r2.x >> 16));
            acc[2] += w2 * bf2f((unsigned short)r2.y);
            acc[3] += w2 * bf2f((unsigned short)(r2.y >> 16));
            acc[4] += w2 * bf2f((unsigned short)r2.z);
            acc[5] += w2 * bf2f((unsigned short)(r2.z >> 16));
            acc[6] += w2 * bf2f((unsigned short)r2.w);
            acc[7] += w2 * bf2f((unsigned short)(r2.w >> 16));
            acc[0] += w3 * bf2f((unsigned short)r3.x);
            acc[1] += w3 * bf2f((unsigned short)(r3.x >> 16));
            acc[2] += w3 * bf2f((unsigned short)r3.y);
            acc[3] += w3 * bf2f((unsigned short)(r3.y >> 16));
            acc[4] += w3 * bf2f((unsigned short)r3.z);
            acc[5] += w3 * bf2f((unsigned short)(r3.z >> 16));
            acc[6] += w3 * bf2f((unsigned short)r3.w);
            acc[7] += w3 * bf2f((unsigned short)(r3.w >> 16));
        }
        for (; p + 3 < s1; p += 4) {
            uint2 e0 = edata[p + hf];
            uint2 e1 = edata[p + 2 + hf];
            float w0 = u2f(e0.y), w1 = u2f(e1.y);
            uint4 r0 = *(const uint4*)(hb + (size_t)e0.x * 256);
            uint4 r1 = *(const uint4*)(hb + (size_t)e1.x * 256);
            acc[0] += w0 * bf2f((unsigned short)r0.x);
            acc[1] += w0 * bf2f((unsigned short)(r0.x >> 16));
            acc[2] += w0 * bf2f((unsigned short)r0.y);
            acc[3] += w0 * bf2f((unsigned short)(r0.y >> 16));
            acc[4] += w0 * bf2f((unsigned short)r0.z);
            acc[5] += w0 * bf2f((unsigned short)(r0.z >> 16));
            acc[6] += w0 * bf2f((unsigned short)r0.w);
            acc[7] += w0 * bf2f((unsigned short)(r0.w >> 16));
            acc[0] += w1 * bf2f((unsigned short)r1.x);
            acc[1] += w1 * bf2f((unsigned short)(r1.x >> 16));
            acc[2] += w1 * bf2f((unsigned short)r1.y);
            acc[3] += w1 * bf2f((unsigned short)(r1.y >> 16));
            acc[4] += w1 * bf2f((unsigned short)r1.z);
            acc[5] += w1 * bf2f((unsigned short)(r1.z >> 16));
            acc[6] += w1 * bf2f((unsigned short)r1.w);
            acc[7] += w1 * bf2f((unsigned short)(r1.w >> 16));
        }
        for (; p < s1; p += 2) {
            int pe = p + hf;
            bool v = pe < s1;
            uint2 e = edata[v ? pe : (s1 - 1)];
            float w = v ? u2f(e.y) : 0.f;
            uint4 r = *(const uint4*)(hb + (size_t)e.x * 256);
            acc[0] += w * bf2f((unsigned short)r.x);
            acc[1] += w * bf2f((unsigned short)(r.x >> 16));
            acc[2] += w * bf2f((unsigned short)r.y);
            acc[3] += w * bf2f((unsigned short)(r.y >> 16));
            acc[4] += w * bf2f((unsigned short)r.z);
            acc[5] += w * bf2f((unsigned short)(r.z >> 16));
            acc[6] += w * bf2f((unsigned short)r.w);
            acc[7] += w * bf2f((unsigned short)(r.w >> 16));
        }
#pragma unroll
        for (int i = 0; i < 8; ++i) acc[i] += __shfl_xor(acc[i], 32, 64);
        if (hf == 0) {
            uint4 o;
            o.x = (unsigned)f2bf(acc[0]) | ((unsigned)f2bf(acc[1]) << 16);
            o.y = (unsigned)f2bf(acc[2]) | ((unsigned)f2bf(acc[3]) << 16);
            o.z = (unsigned)f2bf(acc[4]) | ((unsigned)f2bf(acc[5]) << 16);
            o.w = (unsigned)f2bf(acc[6]) | ((unsigned)f2bf(acc[7]) << 16);
            *(uint4*)(agg + (size_t)node * 256 + sl * 8) = o;
        }
    } else {
        const unsigned short* hb = hsrc + sl * 4;
        float acc[4] = {0.f, 0.f, 0.f, 0.f};
        int p = s0;
        for (; p + 7 < s1; p += 8) {
            uint2 e0 = edata[p + hf];
            uint2 e1 = edata[p + 2 + hf];
            uint2 e2 = edata[p + 4 + hf];
            uint2 e3 = edata[p + 6 + hf];
            float w0 = u2f(e0.y), w1 = u2f(e1.y), w2 = u2f(e2.y), w3 = u2f(e3.y);
            uint2 r0 = *(const uint2*)(hb + (size_t)e0.x * 128);
            uint2 r1 = *(const uint2*)(hb + (size_t)e1.x * 128);
            uint2 r2 = *(const uint2*)(hb + (size_t)e2.x * 128);
            uint2 r3 = *(const uint2*)(hb + (size_t)e3.x * 128);
            acc[0] += w0 * bf2f((unsigned short)r0.x);
            acc[1] += w0 * bf2f((unsigned short)(r0.x >> 16));
            acc[2] += w0 * bf2f((unsigned short)r0.y);
            acc[3] += w0 * bf2f((unsigned short)(r0.y >> 16));
            acc[0] += w1 * bf2f((unsigned short)r1.x);
            acc[1] += w1 * bf2f((unsigned short)(r1.x >> 16));
            acc[2] += w1 * bf2f((unsigned short)r1.y);
            acc[3] += w1 * bf2f((unsigned short)(r1.y >> 16));
            acc[0] += w2 * bf2f((unsigned short)r2.x);
            acc[1] += w2 * bf2f((unsigned short)(r2.x >> 16));
            acc[2] += w2 * bf2f((unsigned short)r2.y);
            acc[3] += w2 * bf2f((unsigned short)(r2.y >> 16));
            acc[0] += w3 * bf2f((unsigned short)r3.x);
            acc[1] += w3 * bf2f((unsigned short)(r3.x >> 16));
            acc[2] += w3 * bf2f((unsigned short)r3.y);
            acc[3] += w3 * bf2f((unsigned short)(r3.y >> 16));
        }
        for (; p + 3 < s1; p += 4) {
            uint2 e0 = edata[p + hf];
            uint2 e1 = edata[p + 2 + hf];
            float w0 = u2f(e0.y), w1 = u2f(e1.y);
            uint2 r0 = *(const uint2*)(hb + (size_t)e0.x * 128);
            uint2 r1 = *(const uint2*)(hb + (size_t)e1.x * 128);
            acc[0] += w0 * bf2f((unsigned short)r0.x);
            acc[1] += w0 * bf2f((unsigned short)(r0.x >> 16));
            acc[2] += w0 * bf2f((unsigned short)r0.y);
            acc[3] += w0 * bf2f((unsigned short)(r0.y >> 16));
            acc[0] += w1 * bf2f((unsigned short)r1.x);
            acc[1] += w1 * bf2f((unsigned short)(r1.x >> 16));
            acc[2] += w1 * bf2f((unsigned short)r1.y);
            acc[3] += w1 * bf2f((unsigned short)(r1.y >> 16));
        }
        for (; p < s1; p += 2) {
            int pe = p + hf;
            bool v = pe < s1;
            uint2 e = edata[v ? pe : (s1 - 1)];
            float w = v ? u2f(e.y) : 0.f;
            uint2 r = *(const uint2*)(hb + (size_t)e.x * 128);
            acc[0] += w * bf2f((unsigned short)r.x);
            acc[1] += w * bf2f((unsigned short)(r.x >> 16));
            acc[2] += w * bf2f((unsigned short)r.y);
            acc[3] += w * bf2f((unsigned short)(r.y >> 16));
        }
#pragma unroll
        for (int i = 0; i < 4; ++i) acc[i] += __shfl_xor(acc[i], 32, 64);
        if (hf == 0) {
            uint2 o;
            o.x = (unsigned)f2bf(acc[0]) | ((unsigned)f2bf(acc[1]) << 16);
            o.y = (unsigned)f2bf(acc[2]) | ((unsigned)f2bf(acc[3]) << 16);
            *(uint2*)(agg + (size_t)node * 128 + sl * 4) = o;
        }
    }
}

// ---------------- MFMA dual GEMM: out = relu([A1|A2] @ Bt^T + bias), bf16 ----------------
// A: LDS-staged (BK=64, XOR chunk-swizzle, linear gload_lds dest). B: loaded
// DIRECTLY global->VGPR per fragment (B is L2-resident; removes half the
// staging loads, halves barrier-drain depth, LDS 32->16 KB).

template <int K>
__global__ __launch_bounds__(256) void gemm_mfma(
    const unsigned short* __restrict__ A1, const unsigned short* __restrict__ A2,
    const unsigned short* __restrict__ Bt, const float* __restrict__ bias,
    unsigned short* __restrict__ out) {
    __shared__ unsigned short As[128 * 64];
    const int bb = blockIdx.x;
    const int chunkid = bb >> 4, ii = bb & 15;
    const int row_t = chunkid * 8 + (ii & 7);
    const int col_t = ii >> 3;
    if (row_t >= NRT) return;
    const int row0 = row_t * 128, col0 = col_t * 128;
    const int t = threadIdx.x;
    const int lane = t & 63;
    const int w = t >> 6;
    const int wr = w >> 1, wc = w & 1;
    const int fr = lane & 15, fq = lane >> 4;

    const int srow = t >> 3;                  // 0..31 within a 32-row round
    const int schunk = (t & 7) ^ (srow & 7);  // swizzled source k-chunk

    int arow_[4];
#pragma unroll
    for (int g = 0; g < 4; ++g) {
        int r = row0 + g * 32 + srow;
        if (r >= N_NODES) r = N_NODES - 1;
        arow_[g] = r;
    }

    // per-lane B row base pointers (n = 0..3), chunk offset fq*8 folded in
    const unsigned short* brow[4];
#pragma unroll
    for (int n = 0; n < 4; ++n)
        brow[n] = Bt + (size_t)(col0 + wc * 64 + n * 16 + fr) * (2 * K) + fq * 8;

    f32x4 acc[4][4] = {};

    constexpr int NT = (2 * K) / 64;
    for (int kt = 0; kt < NT; ++kt) {
        const int kk = kt * 64;
        const unsigned short* Ap;
        int ka;
        if (kk < K) { Ap = A1; ka = kk; } else { Ap = A2; ka = kk - K; }
#pragma unroll
        for (int g = 0; g < 4; ++g)
            gload16(Ap + (size_t)arow_[g] * K + ka + schunk * 8, As + g * 2048 + w * 512);
        // B fragments straight from global (L2-hot) while A staging drains
        bf16x8 b[2][4];
#pragma unroll
        for (int kh = 0; kh < 2; ++kh)
#pragma unroll
            for (int n = 0; n < 4; ++n)
                b[kh][n] = *(const bf16x8*)(brow[n] + kk + kh * 32);
        __syncthreads();
        bf16x8 a[2][4];
#pragma unroll
        for (int kh = 0; kh < 2; ++kh)
#pragma unroll
            for (int m = 0; m < 4; ++m) {
                int row = wr * 64 + m * 16 + fr;
                a[kh][m] = *(const bf16x8*)(As + row * 64 + ((kh * 4 + fq) ^ (row & 7)) * 8);
            }
#pragma unroll
        for (int kh = 0; kh < 2; ++kh)
#pragma unroll
            for (int m = 0; m < 4; ++m)
#pragma unroll
                for (int n = 0; n < 4; ++n)
                    acc[m][n] = __builtin_amdgcn_mfma_f32_16x16x32_bf16(a[kh][m], b[kh][n],
                                                                        acc[m][n], 0, 0, 0);
        __syncthreads();
    }

#pragma unroll
    for (int n = 0; n < 4; ++n) {
        const int col = col0 + wc * 64 + n * 16 + fr;
        const float bv = bias[col];
#pragma unroll
        for (int m = 0; m < 4; ++m) {
            const int rbase = row0 + wr * 64 + m * 16 + fq * 4;
#pragma unroll
            for (int j = 0; j < 4; ++j) {
                const int r = rbase + j;
                if (r < N_NODES)
                    out[(size_t)r * DIM + col] = f2bf(fmaxf(acc[m][n][j] + bv, 0.f));
            }
        }
    }
}

// ---------------- fused pool (sorted batch) + FC head + log_softmax ----------------

__global__ void pool_head_kernel(const unsigned short* __restrict__ h,
                                 const int* __restrict__ batch,
                                 const float* __restrict__ Wfc1, const float* __restrict__ bfc1,
                                 const float* __restrict__ Wfc2, const float* __restrict__ bfc2,
                                 float* __restrict__ out) {
    __shared__ float4 sd[4][64];
    __shared__ float row[DIM];
    __shared__ float fc1[DIM];
    __shared__ float logits[NUM_CLASSES];
    __shared__ float red[2];
    int g = blockIdx.x, t = threadIdx.x;
    int wv = t >> 6, lane = t & 63;
    int lo = 0, hi = N_NODES;
    while (lo < hi) { int m = (lo + hi) >> 1; if (batch[m] < g) lo = m + 1; else hi = m; }
    int start = lo;
    lo = 0; hi = N_NODES;
    while (lo < hi) { int m = (lo + hi) >> 1; if (batch[m] < g + 1) lo = m + 1; else hi = m; }
    int end = lo;
    float4 acc = {0.f, 0.f, 0.f, 0.f};
    for (int i = start + wv; i < end; i += 4) {
        uint2 r = *(const uint2*)(h + (size_t)i * 256 + lane * 4);
        acc.x += bf2f((unsigned short)r.x);
        acc.y += bf2f((unsigned short)(r.x >> 16));
        acc.z += bf2f((unsigned short)r.y);
        acc.w += bf2f((unsigned short)(r.y >> 16));
    }
    sd[wv][lane] = acc;
    __syncthreads();
    if (wv == 0) {
        float4 a = sd[0][lane], b = sd[1][lane], c = sd[2][lane], d = sd[3][lane];
        float4 s;
        s.x = a.x + b.x + c.x + d.x;
        s.y = a.y + b.y + c.y + d.y;
        s.z = a.z + b.z + c.z + d.z;
        s.w = a.w + b.w + c.w + d.w;
        *(float4*)(&row[lane * 4]) = s;
    }
    __syncthreads();
    float a1 = bfc1[t];
    for (int k = 0; k < DIM; ++k) a1 += row[k] * Wfc1[k * DIM + t];
    fc1[t] = fmaxf(a1, 0.f);
    __syncthreads();
    if (t < NUM_CLASSES) {
        float a = bfc2[t];
        for (int k = 0; k < DIM; ++k) a += fc1[k] * Wfc2[k * NUM_CLASSES + t];
        logits[t] = a;
    }
    __syncthreads();
    if (t == 0) {
        float mx = -INFINITY;
        for (int c2 = 0; c2 < NUM_CLASSES; ++c2) mx = fmaxf(mx, logits[c2]);
        float s = 0.f;
        for (int c2 = 0; c2 < NUM_CLASSES; ++c2) s += expf(logits[c2] - mx);
        red[0] = mx;
        red[1] = logf(s);
    }
    __syncthreads();
    if (t < NUM_CLASSES) out[g * NUM_CLASSES + t] = logits[t] - red[0] - red[1];
}

// ---------------- launch ----------------

extern "C" void kernel_launch(void* const* d_in, const int* in_sizes, int n_in,
                              void* d_out, int out_size, void* d_ws, size_t ws_size,
                              hipStream_t stream) {
    const float* x = (const float*)d_in[0];
    const int* ei = (const int*)d_in[1];
    const int* batch = (const int*)d_in[2];
    const float* ew = (const float*)d_in[3];
    const float *Wr[5], *br[5], *Wo[5];
    for (int i = 0; i < 5; ++i) {
        Wr[i] = (const float*)d_in[4 + 3 * i];
        br[i] = (const float*)d_in[5 + 3 * i];
        Wo[i] = (const float*)d_in[6 + 3 * i];
    }
    const float* Wfc1 = (const float*)d_in[19];
    const float* bfc1 = (const float*)d_in[20];
    const float* Wfc2 = (const float*)d_in[21];
    const float* bfc2 = (const float*)d_in[22];
    float* out = (float*)d_out;

    char* ws = (char*)d_ws;
    size_t off = 0;
    auto alloc = [&](size_t bytes) {
        void* p = ws + off;
        off += (bytes + 255) & ~(size_t)255;
        return p;
    };
    unsigned short* xb = (unsigned short*)alloc((size_t)N_NODES * F_IN * 2);
    unsigned short* h0 = (unsigned short*)alloc((size_t)N_NODES * DIM * 2);
    unsigned short* h1 = (unsigned short*)alloc((size_t)N_NODES * DIM * 2);
    unsigned short* aggb = (unsigned short*)alloc((size_t)N_NODES * DIM * 2);
    unsigned short* Bt[5];
    Bt[0] = (unsigned short*)alloc((size_t)2 * F_IN * DIM * 2);
    for (int i = 1; i < 5; ++i) Bt[i] = (unsigned short*)alloc((size_t)2 * DIM * DIM * 2);
    int* offs = (int*)alloc((N_NODES + 1) * 4);
    int* bcnt = (int*)alloc(NBKT * 4);
    int* bbase = (int*)alloc((NBKT + 1) * 4);
    int* gbase = (int*)alloc(NBKT * 4);
    uint2* edata = (uint2*)alloc((size_t)N_EDGES * 8);
    uint2* edata2 = (uint2*)alloc((size_t)N_EDGES * 8);

    const int* src = ei;
    const int* dstp = ei + N_EDGES;

    hipMemsetAsync(bcnt, 0, NBKT * 4, stream);
    bucket_hist<<<(N_EDGES + 4095) / 4096, 256, 0, stream>>>(dstp, bcnt, N_EDGES);
    scan_bkt<<<1, 256, 0, stream>>>(bcnt, bbase, gbase);
    bucket_scatter<<<(N_EDGES + 4095) / 4096, 256, 0, stream>>>(src, dstp, ew, gbase, edata2,
                                                                N_EDGES);
    bucket_sort<<<NBKT, 256, 0, stream>>>(bbase, edata2, edata, offs);

    conv_x<<<((N_NODES * F_IN / 4) + 255) / 256, 256, 0, stream>>>(x, xb, N_NODES * F_IN / 4);
    pack_w<<<(2 * F_IN * DIM + 255) / 256, 256, 0, stream>>>(Wr[0], Wo[0], Bt[0], F_IN);
    {
        dim3 pg((2 * DIM * DIM + 255) / 256, 4);
        pack_w4<<<pg, 256, 0, stream>>>(Wr[1], Wo[1], Wr[2], Wo[2], Wr[3], Wo[3], Wr[4], Wo[4],
                                        Bt[1], Bt[2], Bt[3], Bt[4]);
    }

    const int ggrid = ((NRT + 7) / 8) * 16;  // 16-block chunks of 8 rows x 2 cols

    // layer 1 (K = 128)
    agg_bf16<128><<<(N_NODES + 3) / 4, 256, 0, stream>>>(xb, offs, edata, aggb);
    gemm_mfma<128><<<ggrid, 256, 0, stream>>>(aggb, xb, Bt[0], br[0], h0);

    const unsigned short* hp = h0;
    unsigned short* hn = h1;
    for (int L = 1; L < 5; ++L) {
        agg_bf16<256><<<(N_NODES + 3) / 4, 256, 0, stream>>>(hp, offs, edata, aggb);
        gemm_mfma<256><<<ggrid, 256, 0, stream>>>(aggb, hp, Bt[L], br[L], hn);
        unsigned short* t2 = (unsigned short*)hp;
        hp = hn;
        hn = t2;
    }

    pool_head_kernel<<<NUM_GRAPHS, 256, 0, stream>>>(hp, batch, Wfc1, bfc1, Wfc2, bfc2, out);
}

// Round 17
// 447.222 us; speedup vs baseline: 1.3329x; 1.3329x over previous
//
#include <hip/hip_runtime.h>
#include <hip/hip_bf16.h>

#define N_NODES 50000
#define N_EDGES 800000
#define F_IN 128
#define DIM 256
#define NUM_CLASSES 10
#define NUM_GRAPHS 256
#define NBKT ((N_NODES + 255) / 256)
#define BCAP 8192
#define NRT64 ((N_NODES + 63) / 64)

typedef short bf16x8 __attribute__((ext_vector_type(8)));
typedef float f32x4 __attribute__((ext_vector_type(4)));

__device__ __forceinline__ float bf2f(unsigned short u) {
    union { unsigned int u; float f; } c;
    c.u = ((unsigned int)u) << 16;
    return c.f;
}
__device__ __forceinline__ unsigned short f2bf(float f) {
    union { float f; unsigned int u; } c;
    c.f = f;
    unsigned int r = (c.u + 0x7fffu + ((c.u >> 16) & 1u)) >> 16;
    return (unsigned short)r;
}
__device__ __forceinline__ float u2f(unsigned int u) {
    union { unsigned int u; float f; } c;
    c.u = u;
    return c.f;
}
__device__ __forceinline__ unsigned int f2u(float f) {
    union { float f; unsigned int u; } c;
    c.f = f;
    return c.u;
}

__device__ __forceinline__ void gload16(const unsigned short* g, unsigned short* l) {
    __builtin_amdgcn_global_load_lds(
        (const __attribute__((address_space(1))) unsigned int*)(g),
        (__attribute__((address_space(3))) unsigned int*)(l), 16, 0, 0);
}

// ---------------- CSR build (bucket-level only) ----------------

__global__ void bucket_hist(const int* __restrict__ dst, int* __restrict__ bcnt, int E) {
    __shared__ int c[NBKT];
    int t = threadIdx.x;
    for (int i = t; i < NBKT; i += 256) c[i] = 0;
    __syncthreads();
    int ebase = blockIdx.x * 4096 + t;
#pragma unroll
    for (int i = 0; i < 16; ++i) {
        int e = ebase + i * 256;
        if (e < E) atomicAdd(&c[dst[e] >> 8], 1);
    }
    __syncthreads();
    for (int i = t; i < NBKT; i += 256)
        if (c[i]) atomicAdd(&bcnt[i], c[i]);
}

__global__ void scan_bkt(const int* __restrict__ bcnt, int* __restrict__ bbase,
                         int* __restrict__ gbase) {
    __shared__ int sd[256];
    int t = threadIdx.x;
    int v = (t < NBKT) ? bcnt[t] : 0;
    sd[t] = v;
    __syncthreads();
    for (int off = 1; off < 256; off <<= 1) {
        int u = (t >= off) ? sd[t - off] : 0;
        __syncthreads();
        sd[t] += u;
        __syncthreads();
    }
    if (t < NBKT) {
        int ex = sd[t] - v;
        bbase[t] = ex;
        gbase[t] = ex;
    }
    if (t == NBKT - 1) bbase[NBKT] = sd[t];
}

__global__ __launch_bounds__(256) void bucket_scatter(
    const int* __restrict__ src, const int* __restrict__ dst, const float* __restrict__ ew,
    int* __restrict__ gbase, uint2* __restrict__ edata2, int E) {
    __shared__ int cnt[NBKT];
    __shared__ int base_s[NBKT];
    int t = threadIdx.x;
    int ebase = blockIdx.x * 4096 + t;
    for (int i = t; i < NBKT; i += 256) cnt[i] = 0;
    __syncthreads();
#pragma unroll
    for (int i = 0; i < 16; ++i) {
        int e = ebase + i * 256;
        if (e < E) atomicAdd(&cnt[dst[e] >> 8], 1);
    }
    __syncthreads();
    for (int i = t; i < NBKT; i += 256) {
        int c = cnt[i];
        base_s[i] = c ? atomicAdd(&gbase[i], c) : 0;
        cnt[i] = 0;
    }
    __syncthreads();
#pragma unroll
    for (int i = 0; i < 16; ++i) {
        int e = ebase + i * 256;
        if (e < E) {
            int d = dst[e];
            int bkt = d >> 8;
            int r = atomicAdd(&cnt[bkt], 1);
            edata2[base_s[bkt] + r] =
                make_uint2((unsigned)src[e] | ((unsigned)(d & 255) << 16), f2u(ew[e]));
        }
    }
}

__global__ __launch_bounds__(256) void bucket_sort(
    const int* __restrict__ bbase, const uint2* __restrict__ edata2, uint2* __restrict__ edata,
    int* __restrict__ offs) {
    __shared__ uint2 stage[BCAP];
    __shared__ int cnt[256];
    __shared__ int sd[256];
    int b = blockIdx.x, t = threadIdx.x;
    int lo = bbase[b];
    int hi = bbase[b + 1];
    int ce = hi - lo;
    cnt[t] = 0;
    __syncthreads();
    for (int i = t; i < ce; i += 256) {
        uint2 e = edata2[lo + i];
        atomicAdd(&cnt[(e.x >> 16) & 255], 1);
    }
    __syncthreads();
    int myc = cnt[t];
    sd[t] = myc;
    __syncthreads();
    for (int off = 1; off < 256; off <<= 1) {
        int u = (t >= off) ? sd[t - off] : 0;
        __syncthreads();
        sd[t] += u;
        __syncthreads();
    }
    int ex = sd[t] - myc;
    __syncthreads();
    sd[t] = ex;
    cnt[t] = 0;
    int node = b * 256 + t;
    if (node < N_NODES) offs[node] = lo + ex;
    if (node == N_NODES - 1) offs[N_NODES] = lo + ex + myc;
    __syncthreads();
    if (ce <= BCAP) {
        for (int i = t; i < ce; i += 256) {
            uint2 e = edata2[lo + i];
            int dl = (e.x >> 16) & 255;
            int r = atomicAdd(&cnt[dl], 1);
            stage[sd[dl] + r] = make_uint2(e.x & 0xFFFFu, e.y);
        }
        __syncthreads();
        for (int i = t; i < ce; i += 256) edata[lo + i] = stage[i];
    } else {
        for (int i = t; i < ce; i += 256) {
            uint2 e = edata2[lo + i];
            int dl = (e.x >> 16) & 255;
            int r = atomicAdd(&cnt[dl], 1);
            edata[lo + sd[dl] + r] = make_uint2(e.x & 0xFFFFu, e.y);
        }
    }
}

// ---------------- dtype prep ----------------

__global__ void conv_x(const float* __restrict__ x, unsigned short* __restrict__ xb, int n4) {
    int i = blockIdx.x * blockDim.x + threadIdx.x;
    if (i >= n4) return;
    float4 v = ((const float4*)x)[i];
    ushort4 o;
    o.x = f2bf(v.x); o.y = f2bf(v.y); o.z = f2bf(v.z); o.w = f2bf(v.w);
    ((ushort4*)xb)[i] = o;
}

__global__ void pack_w(const float* __restrict__ Wr, const float* __restrict__ Wo,
                       unsigned short* __restrict__ Bt, int K) {
    int idx = blockIdx.x * blockDim.x + threadIdx.x;
    int total = 2 * K * DIM;
    if (idx >= total) return;
    int k = idx / DIM, c = idx % DIM;
    float v = (k < K) ? Wr[k * DIM + c] : Wo[(k - K) * DIM + c];
    Bt[(size_t)c * (2 * K) + k] = f2bf(v);
}

__global__ void pack_w4(const float* __restrict__ W2r, const float* __restrict__ W2o,
                        const float* __restrict__ W3r, const float* __restrict__ W3o,
                        const float* __restrict__ W4r, const float* __restrict__ W4o,
                        const float* __restrict__ W5r, const float* __restrict__ W5o,
                        unsigned short* __restrict__ B2, unsigned short* __restrict__ B3,
                        unsigned short* __restrict__ B4, unsigned short* __restrict__ B5) {
    int idx = blockIdx.x * blockDim.x + threadIdx.x;
    int total = 2 * DIM * DIM;
    if (idx >= total) return;
    int L = blockIdx.y;
    const float* Wr = (L == 0) ? W2r : (L == 1) ? W3r : (L == 2) ? W4r : W5r;
    const float* Wo = (L == 0) ? W2o : (L == 1) ? W3o : (L == 2) ? W4o : W5o;
    unsigned short* Bt = (L == 0) ? B2 : (L == 1) ? B3 : (L == 2) ? B4 : B5;
    int k = idx / DIM, c = idx % DIM;
    float v = (k < DIM) ? Wr[k * DIM + c] : Wo[(k - DIM) * DIM + c];
    Bt[(size_t)c * (2 * DIM) + k] = f2bf(v);
}

// ---------------- per-node aggregation ----------------
// 2 edges per wave (half-wave hf), 32 sub-lanes x 16B per row, 8-edge unroll.

template <int F>
__global__ void agg_bf16(const unsigned short* __restrict__ hsrc, const int* __restrict__ offs,
                         const uint2* __restrict__ edata, unsigned short* __restrict__ agg) {
    int node = blockIdx.x * (blockDim.x >> 6) + (threadIdx.x >> 6);
    if (node >= N_NODES) return;
    int lane = threadIdx.x & 63;
    int hf = lane >> 5;
    int sl = lane & 31;
    int s0 = offs[node], s1 = offs[node + 1];
    if (F == 256) {
        const unsigned short* hb = hsrc + sl * 8;
        float acc[8] = {0.f, 0.f, 0.f, 0.f, 0.f, 0.f, 0.f, 0.f};
        int p = s0;
        for (; p + 7 < s1; p += 8) {
            uint2 e0 = edata[p + hf];
            uint2 e1 = edata[p + 2 + hf];
            uint2 e2 = edata[p + 4 + hf];
            uint2 e3 = edata[p + 6 + hf];
            float w0 = u2f(e0.y), w1 = u2f(e1.y), w2 = u2f(e2.y), w3 = u2f(e3.y);
            uint4 r0 = *(const uint4*)(hb + (size_t)e0.x * 256);
            uint4 r1 = *(const uint4*)(hb + (size_t)e1.x * 256);
            uint4 r2 = *(const uint4*)(hb + (size_t)e2.x * 256);
            uint4 r3 = *(const uint4*)(hb + (size_t)e3.x * 256);
            acc[0] += w0 * bf2f((unsigned short)r0.x);
            acc[1] += w0 * bf2f((unsigned short)(r0.x >> 16));
            acc[2] += w0 * bf2f((unsigned short)r0.y);
            acc[3] += w0 * bf2f((unsigned short)(r0.y >> 16));
            acc[4] += w0 * bf2f((unsigned short)r0.z);
            acc[5] += w0 * bf2f((unsigned short)(r0.z >> 16));
            acc[6] += w0 * bf2f((unsigned short)r0.w);
            acc[7] += w0 * bf2f((unsigned short)(r0.w >> 16));
            acc[0] += w1 * bf2f((unsigned short)r1.x);
            acc[1] += w1 * bf2f((unsigned short)(r1.x >> 16));
            acc[2] += w1 * bf2f((unsigned short)r1.y);
            acc[3] += w1 * bf2f((unsigned short)(r1.y >> 16));
            acc[4] += w1 * bf2f((unsigned short)r1.z);
            acc[5] += w1 * bf2f((unsigned short)(r1.z >> 16));
            acc[6] += w1 * bf2f((unsigned short)r1.w);
            acc[7] += w1 * bf2f((unsigned short)(r1.w >> 16));
            acc[0] += w2 * bf2f((unsigned short)r2.x);
            acc[1] += w2 * bf2f((unsigned short)(r2.x >> 16));
            acc[2] += w2 * bf2f((unsigned short)r2.y);
            acc[3] += w2 * bf2f((unsigned short)(r2.y >> 16));
            acc[4] += w2 * bf2f((unsigned short)r2.z);
            acc[5] += w2 * bf2f((unsigned short)(r2.z >> 16));
            acc[6] += w2 * bf2f((unsigned short)r2.w);
            acc[7] += w2 * bf2f((unsigned short)(r2.w >> 16));
            acc[0] += w3 * bf2f((unsigned short)r3.x);
            acc[1] += w3 * bf2f((unsigned short)(r3.x >> 16));
            acc[2] += w3 * bf2f((unsigned short)r3.y);
            acc[3] += w3 * bf2f((unsigned short)(r3.y >> 16));
            acc[4] += w3 * bf2f((unsigned short)r3.z);
            acc[5] += w3 * bf2f((unsigned short)(r3.z >> 16));
            acc[6] += w3 * bf2f((unsigned short)r3.w);
            acc[7] += w3 * bf2f((unsigned short)(r3.w >> 16));
        }
        for (; p + 3 < s1; p += 4) {
            uint2 e0 = edata[p + hf];
            uint2 e1 = edata[p + 2 + hf];
            float w0 = u2f(e0.y), w1 = u2f(e1.y);
            uint4 r0 = *(const uint4*)(hb + (size_t)e0.x * 256);
            uint4 r1 = *(const uint4*)(hb + (size_t)e1.x * 256);
            acc[0] += w0 * bf2f((unsigned short)r0.x);
            acc[1] += w0 * bf2f((unsigned short)(r0.x >> 16));
            acc[2] += w0 * bf2f((unsigned short)r0.y);
            acc[3] += w0 * bf2f((unsigned short)(r0.y >> 16));
            acc[4] += w0 * bf2f((unsigned short)r0.z);
            acc[5] += w0 * bf2f((unsigned short)(r0.z >> 16));
            acc[6] += w0 * bf2f((unsigned short)r0.w);
            acc[7] += w0 * bf2f((unsigned short)(r0.w >> 16));
            acc[0] += w1 * bf2f((unsigned short)r1.x);
            acc[1] += w1 * bf2f((unsigned short)(r1.x >> 16));
            acc[2] += w1 * bf2f((unsigned short)r1.y);
            acc[3] += w1 * bf2f((unsigned short)(r1.y >> 16));
            acc[4] += w1 * bf2f((unsigned short)r1.z);
            acc[5] += w1 * bf2f((unsigned short)(r1.z >> 16));
            acc[6] += w1 * bf2f((unsigned short)r1.w);
            acc[7] += w1 * bf2f((unsigned short)(r1.w >> 16));
        }
        for (; p < s1; p += 2) {
            int pe = p + hf;
            bool v = pe < s1;
            uint2 e = edata[v ? pe : (s1 - 1)];
            float w = v ? u2f(e.y) : 0.f;
            uint4 r = *(const uint4*)(hb + (size_t)e.x * 256);
            acc[0] += w * bf2f((unsigned short)r.x);
            acc[1] += w * bf2f((unsigned short)(r.x >> 16));
            acc[2] += w * bf2f((unsigned short)r.y);
            acc[3] += w * bf2f((unsigned short)(r.y >> 16));
            acc[4] += w * bf2f((unsigned short)r.z);
            acc[5] += w * bf2f((unsigned short)(r.z >> 16));
            acc[6] += w * bf2f((unsigned short)r.w);
            acc[7] += w * bf2f((unsigned short)(r.w >> 16));
        }
#pragma unroll
        for (int i = 0; i < 8; ++i) acc[i] += __shfl_xor(acc[i], 32, 64);
        if (hf == 0) {
            uint4 o;
            o.x = (unsigned)f2bf(acc[0]) | ((unsigned)f2bf(acc[1]) << 16);
            o.y = (unsigned)f2bf(acc[2]) | ((unsigned)f2bf(acc[3]) << 16);
            o.z = (unsigned)f2bf(acc[4]) | ((unsigned)f2bf(acc[5]) << 16);
            o.w = (unsigned)f2bf(acc[6]) | ((unsigned)f2bf(acc[7]) << 16);
            *(uint4*)(agg + (size_t)node * 256 + sl * 8) = o;
        }
    } else {
        const unsigned short* hb = hsrc + sl * 4;
        float acc[4] = {0.f, 0.f, 0.f, 0.f};
        int p = s0;
        for (; p + 7 < s1; p += 8) {
            uint2 e0 = edata[p + hf];
            uint2 e1 = edata[p + 2 + hf];
            uint2 e2 = edata[p + 4 + hf];
            uint2 e3 = edata[p + 6 + hf];
            float w0 = u2f(e0.y), w1 = u2f(e1.y), w2 = u2f(e2.y), w3 = u2f(e3.y);
            uint2 r0 = *(const uint2*)(hb + (size_t)e0.x * 128);
            uint2 r1 = *(const uint2*)(hb + (size_t)e1.x * 128);
            uint2 r2 = *(const uint2*)(hb + (size_t)e2.x * 128);
            uint2 r3 = *(const uint2*)(hb + (size_t)e3.x * 128);
            acc[0] += w0 * bf2f((unsigned short)r0.x);
            acc[1] += w0 * bf2f((unsigned short)(r0.x >> 16));
            acc[2] += w0 * bf2f((unsigned short)r0.y);
            acc[3] += w0 * bf2f((unsigned short)(r0.y >> 16));
            acc[0] += w1 * bf2f((unsigned short)r1.x);
            acc[1] += w1 * bf2f((unsigned short)(r1.x >> 16));
            acc[2] += w1 * bf2f((unsigned short)r1.y);
            acc[3] += w1 * bf2f((unsigned short)(r1.y >> 16));
            acc[0] += w2 * bf2f((unsigned short)r2.x);
            acc[1] += w2 * bf2f((unsigned short)(r2.x >> 16));
            acc[2] += w2 * bf2f((unsigned short)r2.y);
            acc[3] += w2 * bf2f((unsigned short)(r2.y >> 16));
            acc[0] += w3 * bf2f((unsigned short)r3.x);
            acc[1] += w3 * bf2f((unsigned short)(r3.x >> 16));
            acc[2] += w3 * bf2f((unsigned short)r3.y);
            acc[3] += w3 * bf2f((unsigned short)(r3.y >> 16));
        }
        for (; p + 3 < s1; p += 4) {
            uint2 e0 = edata[p + hf];
            uint2 e1 = edata[p + 2 + hf];
            float w0 = u2f(e0.y), w1 = u2f(e1.y);
            uint2 r0 = *(const uint2*)(hb + (size_t)e0.x * 128);
            uint2 r1 = *(const uint2*)(hb + (size_t)e1.x * 128);
            acc[0] += w0 * bf2f((unsigned short)r0.x);
            acc[1] += w0 * bf2f((unsigned short)(r0.x >> 16));
            acc[2] += w0 * bf2f((unsigned short)r0.y);
            acc[3] += w0 * bf2f((unsigned short)(r0.y >> 16));
            acc[0] += w1 * bf2f((unsigned short)r1.x);
            acc[1] += w1 * bf2f((unsigned short)(r1.x >> 16));
            acc[2] += w1 * bf2f((unsigned short)r1.y);
            acc[3] += w1 * bf2f((unsigned short)(r1.y >> 16));
        }
        for (; p < s1; p += 2) {
            int pe = p + hf;
            bool v = pe < s1;
            uint2 e = edata[v ? pe : (s1 - 1)];
            float w = v ? u2f(e.y) : 0.f;
            uint2 r = *(const uint2*)(hb + (size_t)e.x * 128);
            acc[0] += w * bf2f((unsigned short)r.x);
            acc[1] += w * bf2f((unsigned short)(r.x >> 16));
            acc[2] += w * bf2f((unsigned short)r.y);
            acc[3] += w * bf2f((unsigned short)(r.y >> 16));
        }
#pragma unroll
        for (int i = 0; i < 4; ++i) acc[i] += __shfl_xor(acc[i], 32, 64);
        if (hf == 0) {
            uint2 o;
            o.x = (unsigned)f2bf(acc[0]) | ((unsigned)f2bf(acc[1]) << 16);
            o.y = (unsigned)f2bf(acc[2]) | ((unsigned)f2bf(acc[3]) << 16);
            *(uint2*)(agg + (size_t)node * 128 + sl * 4) = o;
        }
    }
}

// ---------------- MFMA dual GEMM: out = relu([A1|A2] @ Bt^T + bias), bf16 ----------------
// 64x128 tile, BK=64, XOR chunk-swizzle, A+B LDS-staged (R15 scheme).
// 1568 blocks (~2x occupancy). Epilogue: C staged in LDS (reuse Bs) then
// written as full uint4 row-chunks -> no partial-line write amplification.

template <int K>
__global__ __launch_bounds__(256) void gemm_mfma(
    const unsigned short* __restrict__ A1, const unsigned short* __restrict__ A2,
    const unsigned short* __restrict__ Bt, const float* __restrict__ bias,
    unsigned short* __restrict__ out) {
    __shared__ unsigned short As[64 * 64];
    __shared__ unsigned short Bs[128 * 64];
    const int bb = blockIdx.x;
    const int chunkid = bb >> 4, ii = bb & 15;
    const int row_t = chunkid * 8 + (ii & 7);
    const int col_t = ii >> 3;
    if (row_t >= NRT64) return;
    const int row0 = row_t * 64, col0 = col_t * 128;
    const int t = threadIdx.x;
    const int lane = t & 63;
    const int w = t >> 6;
    const int wr = w >> 1, wc = w & 1;
    const int fr = lane & 15, fq = lane >> 4;

    const int srow = t >> 3;                  // 0..31 within a 32-row round
    const int schunk = (t & 7) ^ (srow & 7);  // swizzled source k-chunk

    int arow_[2];
#pragma unroll
    for (int g = 0; g < 2; ++g) {
        int r = row0 + g * 32 + srow;
        if (r >= N_NODES) r = N_NODES - 1;
        arow_[g] = r;
    }

    f32x4 acc[2][4] = {};

    constexpr int NT = (2 * K) / 64;
    for (int kt = 0; kt < NT; ++kt) {
        const int kk = kt * 64;
        const unsigned short* Ap;
        int ka;
        if (kk < K) { Ap = A1; ka = kk; } else { Ap = A2; ka = kk - K; }
#pragma unroll
        for (int g = 0; g < 2; ++g)
            gload16(Ap + (size_t)arow_[g] * K + ka + schunk * 8, As + g * 2048 + w * 512);
#pragma unroll
        for (int g = 0; g < 4; ++g)
            gload16(Bt + (size_t)(col0 + g * 32 + srow) * (2 * K) + kk + schunk * 8,
                    Bs + g * 2048 + w * 512);
        __syncthreads();
        bf16x8 a[2][2], b[2][4];
#pragma unroll
        for (int kh = 0; kh < 2; ++kh) {
#pragma unroll
            for (int m = 0; m < 2; ++m) {
                int row = wr * 32 + m * 16 + fr;
                a[kh][m] = *(const bf16x8*)(As + row * 64 + ((kh * 4 + fq) ^ (row & 7)) * 8);
            }
#pragma unroll
            for (int n = 0; n < 4; ++n) {
                int row = wc * 64 + n * 16 + fr;
                b[kh][n] = *(const bf16x8*)(Bs + row * 64 + ((kh * 4 + fq) ^ (row & 7)) * 8);
            }
        }
#pragma unroll
        for (int kh = 0; kh < 2; ++kh)
#pragma unroll
            for (int m = 0; m < 2; ++m)
#pragma unroll
                for (int n = 0; n < 4; ++n)
                    acc[m][n] = __builtin_amdgcn_mfma_f32_16x16x32_bf16(a[kh][m], b[kh][n],
                                                                        acc[m][n], 0, 0, 0);
        __syncthreads();
    }

    // epilogue: C tile -> LDS (reuse Bs: 64 rows x 128 cols shorts = 16 KB)
    unsigned short* cs = Bs;
#pragma unroll
    for (int n = 0; n < 4; ++n) {
        const int col = wc * 64 + n * 16 + fr;
        const float bv = bias[col0 + col];
#pragma unroll
        for (int m = 0; m < 2; ++m) {
            const int rl = wr * 32 + m * 16 + fq * 4;
#pragma unroll
            for (int j = 0; j < 4; ++j)
                cs[(rl + j) * 128 + col] = f2bf(fmaxf(acc[m][n][j] + bv, 0.f));
        }
    }
    __syncthreads();
#pragma unroll
    for (int pass = 0; pass < 4; ++pass) {
        int idx = pass * 256 + t;
        int cr = idx >> 4;
        int cc = (idx & 15) * 8;
        int r = row0 + cr;
        if (r < N_NODES)
            *(uint4*)(out + (size_t)r * DIM + col0 + cc) = *(const uint4*)(cs + cr * 128 + cc);
    }
}

// ---------------- fused pool (sorted batch) + FC head + log_softmax ----------------

__global__ void pool_head_kernel(const unsigned short* __restrict__ h,
                                 const int* __restrict__ batch,
                                 const float* __restrict__ Wfc1, const float* __restrict__ bfc1,
                                 const float* __restrict__ Wfc2, const float* __restrict__ bfc2,
                                 float* __restrict__ out) {
    __shared__ float4 sd[4][64];
    __shared__ float row[DIM];
    __shared__ float fc1[DIM];
    __shared__ float logits[NUM_CLASSES];
    __shared__ float red[2];
    int g = blockIdx.x, t = threadIdx.x;
    int wv = t >> 6, lane = t & 63;
    int lo = 0, hi = N_NODES;
    while (lo < hi) { int m = (lo + hi) >> 1; if (batch[m] < g) lo = m + 1; else hi = m; }
    int start = lo;
    lo = 0; hi = N_NODES;
    while (lo < hi) { int m = (lo + hi) >> 1; if (batch[m] < g + 1) lo = m + 1; else hi = m; }
    int end = lo;
    float4 acc = {0.f, 0.f, 0.f, 0.f};
    for (int i = start + wv; i < end; i += 4) {
        uint2 r = *(const uint2*)(h + (size_t)i * 256 + lane * 4);
        acc.x += bf2f((unsigned short)r.x);
        acc.y += bf2f((unsigned short)(r.x >> 16));
        acc.z += bf2f((unsigned short)r.y);
        acc.w += bf2f((unsigned short)(r.y >> 16));
    }
    sd[wv][lane] = acc;
    __syncthreads();
    if (wv == 0) {
        float4 a = sd[0][lane], b = sd[1][lane], c = sd[2][lane], d = sd[3][lane];
        float4 s;
        s.x = a.x + b.x + c.x + d.x;
        s.y = a.y + b.y + c.y + d.y;
        s.z = a.z + b.z + c.z + d.z;
        s.w = a.w + b.w + c.w + d.w;
        *(float4*)(&row[lane * 4]) = s;
    }
    __syncthreads();
    float a1 = bfc1[t];
    for (int k = 0; k < DIM; ++k) a1 += row[k] * Wfc1[k * DIM + t];
    fc1[t] = fmaxf(a1, 0.f);
    __syncthreads();
    if (t < NUM_CLASSES) {
        float a = bfc2[t];
        for (int k = 0; k < DIM; ++k) a += fc1[k] * Wfc2[k * NUM_CLASSES + t];
        logits[t] = a;
    }
    __syncthreads();
    if (t == 0) {
        float mx = -INFINITY;
        for (int c2 = 0; c2 < NUM_CLASSES; ++c2) mx = fmaxf(mx, logits[c2]);
        float s = 0.f;
        for (int c2 = 0; c2 < NUM_CLASSES; ++c2) s += expf(logits[c2] - mx);
        red[0] = mx;
        red[1] = logf(s);
    }
    __syncthreads();
    if (t < NUM_CLASSES) out[g * NUM_CLASSES + t] = logits[t] - red[0] - red[1];
}

// ---------------- launch ----------------

extern "C" void kernel_launch(void* const* d_in, const int* in_sizes, int n_in,
                              void* d_out, int out_size, void* d_ws, size_t ws_size,
                              hipStream_t stream) {
    const float* x = (const float*)d_in[0];
    const int* ei = (const int*)d_in[1];
    const int* batch = (const int*)d_in[2];
    const float* ew = (const float*)d_in[3];
    const float *Wr[5], *br[5], *Wo[5];
    for (int i = 0; i < 5; ++i) {
        Wr[i] = (const float*)d_in[4 + 3 * i];
        br[i] = (const float*)d_in[5 + 3 * i];
        Wo[i] = (const float*)d_in[6 + 3 * i];
    }
    const float* Wfc1 = (const float*)d_in[19];
    const float* bfc1 = (const float*)d_in[20];
    const float* Wfc2 = (const float*)d_in[21];
    const float* bfc2 = (const float*)d_in[22];
    float* out = (float*)d_out;

    char* ws = (char*)d_ws;
    size_t off = 0;
    auto alloc = [&](size_t bytes) {
        void* p = ws + off;
        off += (bytes + 255) & ~(size_t)255;
        return p;
    };
    unsigned short* xb = (unsigned short*)alloc((size_t)N_NODES * F_IN * 2);
    unsigned short* h0 = (unsigned short*)alloc((size_t)N_NODES * DIM * 2);
    unsigned short* h1 = (unsigned short*)alloc((size_t)N_NODES * DIM * 2);
    unsigned short* aggb = (unsigned short*)alloc((size_t)N_NODES * DIM * 2);
    unsigned short* Bt[5];
    Bt[0] = (unsigned short*)alloc((size_t)2 * F_IN * DIM * 2);
    for (int i = 1; i < 5; ++i) Bt[i] = (unsigned short*)alloc((size_t)2 * DIM * DIM * 2);
    int* offs = (int*)alloc((N_NODES + 1) * 4);
    int* bcnt = (int*)alloc(NBKT * 4);
    int* bbase = (int*)alloc((NBKT + 1) * 4);
    int* gbase = (int*)alloc(NBKT * 4);
    uint2* edata = (uint2*)alloc((size_t)N_EDGES * 8);
    uint2* edata2 = (uint2*)alloc((size_t)N_EDGES * 8);

    const int* src = ei;
    const int* dstp = ei + N_EDGES;

    hipMemsetAsync(bcnt, 0, NBKT * 4, stream);
    bucket_hist<<<(N_EDGES + 4095) / 4096, 256, 0, stream>>>(dstp, bcnt, N_EDGES);
    scan_bkt<<<1, 256, 0, stream>>>(bcnt, bbase, gbase);
    bucket_scatter<<<(N_EDGES + 4095) / 4096, 256, 0, stream>>>(src, dstp, ew, gbase, edata2,
                                                                N_EDGES);
    bucket_sort<<<NBKT, 256, 0, stream>>>(bbase, edata2, edata, offs);

    conv_x<<<((N_NODES * F_IN / 4) + 255) / 256, 256, 0, stream>>>(x, xb, N_NODES * F_IN / 4);
    pack_w<<<(2 * F_IN * DIM + 255) / 256, 256, 0, stream>>>(Wr[0], Wo[0], Bt[0], F_IN);
    {
        dim3 pg((2 * DIM * DIM + 255) / 256, 4);
        pack_w4<<<pg, 256, 0, stream>>>(Wr[1], Wo[1], Wr[2], Wo[2], Wr[3], Wo[3], Wr[4], Wo[4],
                                        Bt[1], Bt[2], Bt[3], Bt[4]);
    }

    const int ggrid = ((NRT64 + 7) / 8) * 16;  // 16-block chunks of 8 rows x 2 cols

    // layer 1 (K = 128)
    agg_bf16<128><<<(N_NODES + 3) / 4, 256, 0, stream>>>(xb, offs, edata, aggb);
    gemm_mfma<128><<<ggrid, 256, 0, stream>>>(aggb, xb, Bt[0], br[0], h0);

    const unsigned short* hp = h0;
    unsigned short* hn = h1;
    for (int L = 1; L < 5; ++L) {
        agg_bf16<256><<<(N_NODES + 3) / 4, 256, 0, stream>>>(hp, offs, edata, aggb);
        gemm_mfma<256><<<ggrid, 256, 0, stream>>>(aggb, hp, Bt[L], br[L], hn);
        unsigned short* t2 = (unsigned short*)hp;
        hp = hn;
        hn = t2;
    }

    pool_head_kernel<<<NUM_GRAPHS, 256, 0, stream>>>(hp, batch, Wfc1, bfc1, Wfc2, bfc2, out);
}

// Round 18
// 442.013 us; speedup vs baseline: 1.3486x; 1.0118x over previous
//
#include <hip/hip_runtime.h>
#include <hip/hip_bf16.h>

#define N_NODES 50000
#define N_EDGES 800000
#define F_IN 128
#define DIM 256
#define NUM_CLASSES 10
#define NUM_GRAPHS 256
#define NBKT ((N_NODES + 255) / 256)
#define BCAP 8192
#define NRT64 ((N_NODES + 63) / 64)
#define NEB ((N_EDGES + 4095) / 4096)

typedef short bf16x8 __attribute__((ext_vector_type(8)));
typedef float f32x4 __attribute__((ext_vector_type(4)));

__device__ __forceinline__ float bf2f(unsigned short u) {
    union { unsigned int u; float f; } c;
    c.u = ((unsigned int)u) << 16;
    return c.f;
}
__device__ __forceinline__ unsigned short f2bf(float f) {
    union { float f; unsigned int u; } c;
    c.f = f;
    unsigned int r = (c.u + 0x7fffu + ((c.u >> 16) & 1u)) >> 16;
    return (unsigned short)r;
}
__device__ __forceinline__ float u2f(unsigned int u) {
    union { unsigned int u; float f; } c;
    c.u = u;
    return c.f;
}
__device__ __forceinline__ unsigned int f2u(float f) {
    union { float f; unsigned int u; } c;
    c.f = f;
    return c.u;
}

__device__ __forceinline__ void gload16(const unsigned short* g, unsigned short* l) {
    __builtin_amdgcn_global_load_lds(
        (const __attribute__((address_space(1))) unsigned int*)(g),
        (__attribute__((address_space(3))) unsigned int*)(l), 16, 0, 0);
}

// ---------------- CSR build (bucket-level only) ----------------

// per-block bucket histogram; also saves per-(block,bucket) counts for scatter
__global__ void bucket_hist(const int* __restrict__ dst, int* __restrict__ bcnt,
                            int* __restrict__ blockcnt, int E) {
    __shared__ int c[NBKT];
    int t = threadIdx.x;
    for (int i = t; i < NBKT; i += 256) c[i] = 0;
    __syncthreads();
    int ebase = blockIdx.x * 4096 + t;
#pragma unroll
    for (int i = 0; i < 16; ++i) {
        int e = ebase + i * 256;
        if (e < E) atomicAdd(&c[dst[e] >> 8], 1);
    }
    __syncthreads();
    int* bc = blockcnt + blockIdx.x * NBKT;
    for (int i = t; i < NBKT; i += 256) {
        int v = c[i];
        bc[i] = v;
        if (v) atomicAdd(&bcnt[i], v);
    }
}

__global__ void scan_bkt(const int* __restrict__ bcnt, int* __restrict__ bbase,
                         int* __restrict__ gbase) {
    __shared__ int sd[256];
    int t = threadIdx.x;
    int v = (t < NBKT) ? bcnt[t] : 0;
    sd[t] = v;
    __syncthreads();
    for (int off = 1; off < 256; off <<= 1) {
        int u = (t >= off) ? sd[t - off] : 0;
        __syncthreads();
        sd[t] += u;
        __syncthreads();
    }
    if (t < NBKT) {
        int ex = sd[t] - v;
        bbase[t] = ex;
        gbase[t] = ex;
    }
    if (t == NBKT - 1) bbase[NBKT] = sd[t];
}

// scatter using precomputed per-(block,bucket) counts (no recount pass)
__global__ __launch_bounds__(256) void bucket_scatter(
    const int* __restrict__ src, const int* __restrict__ dst, const float* __restrict__ ew,
    const int* __restrict__ blockcnt, int* __restrict__ gbase, uint2* __restrict__ edata2,
    int E) {
    __shared__ int cnt[NBKT];
    __shared__ int base_s[NBKT];
    int t = threadIdx.x;
    int ebase = blockIdx.x * 4096 + t;
    const int* bc = blockcnt + blockIdx.x * NBKT;
    for (int i = t; i < NBKT; i += 256) {
        int c = bc[i];
        base_s[i] = c ? atomicAdd(&gbase[i], c) : 0;
        cnt[i] = 0;
    }
    __syncthreads();
#pragma unroll
    for (int i = 0; i < 16; ++i) {
        int e = ebase + i * 256;
        if (e < E) {
            int d = dst[e];
            int bkt = d >> 8;
            int r = atomicAdd(&cnt[bkt], 1);
            edata2[base_s[bkt] + r] =
                make_uint2((unsigned)src[e] | ((unsigned)(d & 255) << 16), f2u(ew[e]));
        }
    }
}

__global__ __launch_bounds__(256) void bucket_sort(
    const int* __restrict__ bbase, const uint2* __restrict__ edata2, uint2* __restrict__ edata,
    int* __restrict__ offs) {
    __shared__ uint2 stage[BCAP];
    __shared__ int cnt[256];
    __shared__ int sd[256];
    int b = blockIdx.x, t = threadIdx.x;
    int lo = bbase[b];
    int hi = bbase[b + 1];
    int ce = hi - lo;
    cnt[t] = 0;
    __syncthreads();
    for (int i = t; i < ce; i += 256) {
        uint2 e = edata2[lo + i];
        atomicAdd(&cnt[(e.x >> 16) & 255], 1);
    }
    __syncthreads();
    int myc = cnt[t];
    sd[t] = myc;
    __syncthreads();
    for (int off = 1; off < 256; off <<= 1) {
        int u = (t >= off) ? sd[t - off] : 0;
        __syncthreads();
        sd[t] += u;
        __syncthreads();
    }
    int ex = sd[t] - myc;
    __syncthreads();
    sd[t] = ex;
    cnt[t] = 0;
    int node = b * 256 + t;
    if (node < N_NODES) offs[node] = lo + ex;
    if (node == N_NODES - 1) offs[N_NODES] = lo + ex + myc;
    __syncthreads();
    if (ce <= BCAP) {
        for (int i = t; i < ce; i += 256) {
            uint2 e = edata2[lo + i];
            int dl = (e.x >> 16) & 255;
            int r = atomicAdd(&cnt[dl], 1);
            stage[sd[dl] + r] = make_uint2(e.x & 0xFFFFu, e.y);
        }
        __syncthreads();
        for (int i = t; i < ce; i += 256) edata[lo + i] = stage[i];
    } else {
        for (int i = t; i < ce; i += 256) {
            uint2 e = edata2[lo + i];
            int dl = (e.x >> 16) & 255;
            int r = atomicAdd(&cnt[dl], 1);
            edata[lo + sd[dl] + r] = make_uint2(e.x & 0xFFFFu, e.y);
        }
    }
}

// ---------------- fused dtype prep: conv_x + all weight packs ----------------
// block ranges: [0, NCONV) conv_x ; [NCONV, NCONV+NP1) pack L1 ;
// [NCONV+NP1, NCONV+NP1+4*NP2) pack L2-5.
#define NCONV ((N_NODES * F_IN / 4 + 255) / 256)
#define NP1 ((2 * F_IN * DIM + 255) / 256)
#define NP2 ((2 * DIM * DIM + 255) / 256)

__global__ void prep_kernel(const float* __restrict__ x, unsigned short* __restrict__ xb,
                            const float* __restrict__ W1r, const float* __restrict__ W1o,
                            const float* __restrict__ W2r, const float* __restrict__ W2o,
                            const float* __restrict__ W3r, const float* __restrict__ W3o,
                            const float* __restrict__ W4r, const float* __restrict__ W4o,
                            const float* __restrict__ W5r, const float* __restrict__ W5o,
                            unsigned short* __restrict__ B1, unsigned short* __restrict__ B2,
                            unsigned short* __restrict__ B3, unsigned short* __restrict__ B4,
                            unsigned short* __restrict__ B5) {
    int b = blockIdx.x;
    int t = threadIdx.x;
    if (b < NCONV) {
        int i = b * 256 + t;
        if (i < N_NODES * F_IN / 4) {
            float4 v = ((const float4*)x)[i];
            ushort4 o;
            o.x = f2bf(v.x); o.y = f2bf(v.y); o.z = f2bf(v.z); o.w = f2bf(v.w);
            ((ushort4*)xb)[i] = o;
        }
        return;
    }
    b -= NCONV;
    if (b < NP1) {
        int idx = b * 256 + t;
        if (idx < 2 * F_IN * DIM) {
            int k = idx / DIM, c = idx % DIM;
            float v = (k < F_IN) ? W1r[k * DIM + c] : W1o[(k - F_IN) * DIM + c];
            B1[(size_t)c * (2 * F_IN) + k] = f2bf(v);
        }
        return;
    }
    b -= NP1;
    int L = b / NP2;
    int idx = (b - L * NP2) * 256 + t;
    if (idx >= 2 * DIM * DIM) return;
    const float* Wr = (L == 0) ? W2r : (L == 1) ? W3r : (L == 2) ? W4r : W5r;
    const float* Wo = (L == 0) ? W2o : (L == 1) ? W3o : (L == 2) ? W4o : W5o;
    unsigned short* Bt = (L == 0) ? B2 : (L == 1) ? B3 : (L == 2) ? B4 : B5;
    int k = idx / DIM, c = idx % DIM;
    float v = (k < DIM) ? Wr[k * DIM + c] : Wo[(k - DIM) * DIM + c];
    Bt[(size_t)c * (2 * DIM) + k] = f2bf(v);
}

// ---------------- per-node aggregation ----------------
// 2 edges per wave (half-wave hf), 32 sub-lanes x 16B per row, 8-edge unroll.

template <int F>
__global__ void agg_bf16(const unsigned short* __restrict__ hsrc, const int* __restrict__ offs,
                         const uint2* __restrict__ edata, unsigned short* __restrict__ agg) {
    int node = blockIdx.x * (blockDim.x >> 6) + (threadIdx.x >> 6);
    if (node >= N_NODES) return;
    int lane = threadIdx.x & 63;
    int hf = lane >> 5;
    int sl = lane & 31;
    int s0 = offs[node], s1 = offs[node + 1];
    if (F == 256) {
        const unsigned short* hb = hsrc + sl * 8;
        float acc[8] = {0.f, 0.f, 0.f, 0.f, 0.f, 0.f, 0.f, 0.f};
        int p = s0;
        for (; p + 7 < s1; p += 8) {
            uint2 e0 = edata[p + hf];
            uint2 e1 = edata[p + 2 + hf];
            uint2 e2 = edata[p + 4 + hf];
            uint2 e3 = edata[p + 6 + hf];
            float w0 = u2f(e0.y), w1 = u2f(e1.y), w2 = u2f(e2.y), w3 = u2f(e3.y);
            uint4 r0 = *(const uint4*)(hb + (size_t)e0.x * 256);
            uint4 r1 = *(const uint4*)(hb + (size_t)e1.x * 256);
            uint4 r2 = *(const uint4*)(hb + (size_t)e2.x * 256);
            uint4 r3 = *(const uint4*)(hb + (size_t)e3.x * 256);
            acc[0] += w0 * bf2f((unsigned short)r0.x);
            acc[1] += w0 * bf2f((unsigned short)(r0.x >> 16));
            acc[2] += w0 * bf2f((unsigned short)r0.y);
            acc[3] += w0 * bf2f((unsigned short)(r0.y >> 16));
            acc[4] += w0 * bf2f((unsigned short)r0.z);
            acc[5] += w0 * bf2f((unsigned short)(r0.z >> 16));
            acc[6] += w0 * bf2f((unsigned short)r0.w);
            acc[7] += w0 * bf2f((unsigned short)(r0.w >> 16));
            acc[0] += w1 * bf2f((unsigned short)r1.x);
            acc[1] += w1 * bf2f((unsigned short)(r1.x >> 16));
            acc[2] += w1 * bf2f((unsigned short)r1.y);
            acc[3] += w1 * bf2f((unsigned short)(r1.y >> 16));
            acc[4] += w1 * bf2f((unsigned short)r1.z);
            acc[5] += w1 * bf2f((unsigned short)(r1.z >> 16));
            acc[6] += w1 * bf2f((unsigned short)r1.w);
            acc[7] += w1 * bf2f((unsigned short)(r1.w >> 16));
            acc[0] += w2 * bf2f((unsigned short)r2.x);
            acc[1] += w2 * bf2f((unsigned short)(r2.x >> 16));
            acc[2] += w2 * bf2f((unsigned short)r2.y);
            acc[3] += w2 * bf2f((unsigned short)(r2.y >> 16));
            acc[4] += w2 * bf2f((unsigned short)r2.z);
            acc[5] += w2 * bf2f((unsigned short)(r2.z >> 16));
            acc[6] += w2 * bf2f((unsigned short)r2.w);
            acc[7] += w2 * bf2f((unsigned short)(r2.w >> 16));
            acc[0] += w3 * bf2f((unsigned short)r3.x);
            acc[1] += w3 * bf2f((unsigned short)(r3.x >> 16));
            acc[2] += w3 * bf2f((unsigned short)r3.y);
            acc[3] += w3 * bf2f((unsigned short)(r3.y >> 16));
            acc[4] += w3 * bf2f((unsigned short)r3.z);
            acc[5] += w3 * bf2f((unsigned short)(r3.z >> 16));
            acc[6] += w3 * bf2f((unsigned short)r3.w);
            acc[7] += w3 * bf2f((unsigned short)(r3.w >> 16));
        }
        for (; p + 3 < s1; p += 4) {
            uint2 e0 = edata[p + hf];
            uint2 e1 = edata[p + 2 + hf];
            float w0 = u2f(e0.y), w1 = u2f(e1.y);
            uint4 r0 = *(const uint4*)(hb + (size_t)e0.x * 256);
            uint4 r1 = *(const uint4*)(hb + (size_t)e1.x * 256);
            acc[0] += w0 * bf2f((unsigned short)r0.x);
            acc[1] += w0 * bf2f((unsigned short)(r0.x >> 16));
            acc[2] += w0 * bf2f((unsigned short)r0.y);
            acc[3] += w0 * bf2f((unsigned short)(r0.y >> 16));
            acc[4] += w0 * bf2f((unsigned short)r0.z);
            acc[5] += w0 * bf2f((unsigned short)(r0.z >> 16));
            acc[6] += w0 * bf2f((unsigned short)r0.w);
            acc[7] += w0 * bf2f((unsigned short)(r0.w >> 16));
            acc[0] += w1 * bf2f((unsigned short)r1.x);
            acc[1] += w1 * bf2f((unsigned short)(r1.x >> 16));
            acc[2] += w1 * bf2f((unsigned short)r1.y);
            acc[3] += w1 * bf2f((unsigned short)(r1.y >> 16));
            acc[4] += w1 * bf2f((unsigned short)r1.z);
            acc[5] += w1 * bf2f((unsigned short)(r1.z >> 16));
            acc[6] += w1 * bf2f((unsigned short)r1.w);
            acc[7] += w1 * bf2f((unsigned short)(r1.w >> 16));
        }
        for (; p < s1; p += 2) {
            int pe = p + hf;
            bool v = pe < s1;
            uint2 e = edata[v ? pe : (s1 - 1)];
            float w = v ? u2f(e.y) : 0.f;
            uint4 r = *(const uint4*)(hb + (size_t)e.x * 256);
            acc[0] += w * bf2f((unsigned short)r.x);
            acc[1] += w * bf2f((unsigned short)(r.x >> 16));
            acc[2] += w * bf2f((unsigned short)r.y);
            acc[3] += w * bf2f((unsigned short)(r.y >> 16));
            acc[4] += w * bf2f((unsigned short)r.z);
            acc[5] += w * bf2f((unsigned short)(r.z >> 16));
            acc[6] += w * bf2f((unsigned short)r.w);
            acc[7] += w * bf2f((unsigned short)(r.w >> 16));
        }
#pragma unroll
        for (int i = 0; i < 8; ++i) acc[i] += __shfl_xor(acc[i], 32, 64);
        if (hf == 0) {
            uint4 o;
            o.x = (unsigned)f2bf(acc[0]) | ((unsigned)f2bf(acc[1]) << 16);
            o.y = (unsigned)f2bf(acc[2]) | ((unsigned)f2bf(acc[3]) << 16);
            o.z = (unsigned)f2bf(acc[4]) | ((unsigned)f2bf(acc[5]) << 16);
            o.w = (unsigned)f2bf(acc[6]) | ((unsigned)f2bf(acc[7]) << 16);
            *(uint4*)(agg + (size_t)node * 256 + sl * 8) = o;
        }
    } else {
        const unsigned short* hb = hsrc + sl * 4;
        float acc[4] = {0.f, 0.f, 0.f, 0.f};
        int p = s0;
        for (; p + 7 < s1; p += 8) {
            uint2 e0 = edata[p + hf];
            uint2 e1 = edata[p + 2 + hf];
            uint2 e2 = edata[p + 4 + hf];
            uint2 e3 = edata[p + 6 + hf];
            float w0 = u2f(e0.y), w1 = u2f(e1.y), w2 = u2f(e2.y), w3 = u2f(e3.y);
            uint2 r0 = *(const uint2*)(hb + (size_t)e0.x * 128);
            uint2 r1 = *(const uint2*)(hb + (size_t)e1.x * 128);
            uint2 r2 = *(const uint2*)(hb + (size_t)e2.x * 128);
            uint2 r3 = *(const uint2*)(hb + (size_t)e3.x * 128);
            acc[0] += w0 * bf2f((unsigned short)r0.x);
            acc[1] += w0 * bf2f((unsigned short)(r0.x >> 16));
            acc[2] += w0 * bf2f((unsigned short)r0.y);
            acc[3] += w0 * bf2f((unsigned short)(r0.y >> 16));
            acc[0] += w1 * bf2f((unsigned short)r1.x);
            acc[1] += w1 * bf2f((unsigned short)(r1.x >> 16));
            acc[2] += w1 * bf2f((unsigned short)r1.y);
            acc[3] += w1 * bf2f((unsigned short)(r1.y >> 16));
            acc[0] += w2 * bf2f((unsigned short)r2.x);
            acc[1] += w2 * bf2f((unsigned short)(r2.x >> 16));
            acc[2] += w2 * bf2f((unsigned short)r2.y);
            acc[3] += w2 * bf2f((unsigned short)(r2.y >> 16));
            acc[0] += w3 * bf2f((unsigned short)r3.x);
            acc[1] += w3 * bf2f((unsigned short)(r3.x >> 16));
            acc[2] += w3 * bf2f((unsigned short)r3.y);
            acc[3] += w3 * bf2f((unsigned short)(r3.y >> 16));
        }
        for (; p + 3 < s1; p += 4) {
            uint2 e0 = edata[p + hf];
            uint2 e1 = edata[p + 2 + hf];
            float w0 = u2f(e0.y), w1 = u2f(e1.y);
            uint2 r0 = *(const uint2*)(hb + (size_t)e0.x * 128);
            uint2 r1 = *(const uint2*)(hb + (size_t)e1.x * 128);
            acc[0] += w0 * bf2f((unsigned short)r0.x);
            acc[1] += w0 * bf2f((unsigned short)(r0.x >> 16));
            acc[2] += w0 * bf2f((unsigned short)r0.y);
            acc[3] += w0 * bf2f((unsigned short)(r0.y >> 16));
            acc[0] += w1 * bf2f((unsigned short)r1.x);
            acc[1] += w1 * bf2f((unsigned short)(r1.x >> 16));
            acc[2] += w1 * bf2f((unsigned short)r1.y);
            acc[3] += w1 * bf2f((unsigned short)(r1.y >> 16));
        }
        for (; p < s1; p += 2) {
            int pe = p + hf;
            bool v = pe < s1;
            uint2 e = edata[v ? pe : (s1 - 1)];
            float w = v ? u2f(e.y) : 0.f;
            uint2 r = *(const uint2*)(hb + (size_t)e.x * 128);
            acc[0] += w * bf2f((unsigned short)r.x);
            acc[1] += w * bf2f((unsigned short)(r.x >> 16));
            acc[2] += w * bf2f((unsigned short)r.y);
            acc[3] += w * bf2f((unsigned short)(r.y >> 16));
        }
#pragma unroll
        for (int i = 0; i < 4; ++i) acc[i] += __shfl_xor(acc[i], 32, 64);
        if (hf == 0) {
            uint2 o;
            o.x = (unsigned)f2bf(acc[0]) | ((unsigned)f2bf(acc[1]) << 16);
            o.y = (unsigned)f2bf(acc[2]) | ((unsigned)f2bf(acc[3]) << 16);
            *(uint2*)(agg + (size_t)node * 128 + sl * 4) = o;
        }
    }
}

// ---------------- MFMA dual GEMM: out = relu([A1|A2] @ Bt^T + bias), bf16 ----------------
// 64x128 tile, BK=64, XOR chunk-swizzle, A+B LDS-staged, coalesced LDS epilogue.

template <int K>
__global__ __launch_bounds__(256) void gemm_mfma(
    const unsigned short* __restrict__ A1, const unsigned short* __restrict__ A2,
    const unsigned short* __restrict__ Bt, const float* __restrict__ bias,
    unsigned short* __restrict__ out) {
    __shared__ unsigned short As[64 * 64];
    __shared__ unsigned short Bs[128 * 64];
    const int bb = blockIdx.x;
    const int chunkid = bb >> 4, ii = bb & 15;
    const int row_t = chunkid * 8 + (ii & 7);
    const int col_t = ii >> 3;
    if (row_t >= NRT64) return;
    const int row0 = row_t * 64, col0 = col_t * 128;
    const int t = threadIdx.x;
    const int lane = t & 63;
    const int w = t >> 6;
    const int wr = w >> 1, wc = w & 1;
    const int fr = lane & 15, fq = lane >> 4;

    const int srow = t >> 3;
    const int schunk = (t & 7) ^ (srow & 7);

    int arow_[2];
#pragma unroll
    for (int g = 0; g < 2; ++g) {
        int r = row0 + g * 32 + srow;
        if (r >= N_NODES) r = N_NODES - 1;
        arow_[g] = r;
    }

    f32x4 acc[2][4] = {};

    constexpr int NT = (2 * K) / 64;
    for (int kt = 0; kt < NT; ++kt) {
        const int kk = kt * 64;
        const unsigned short* Ap;
        int ka;
        if (kk < K) { Ap = A1; ka = kk; } else { Ap = A2; ka = kk - K; }
#pragma unroll
        for (int g = 0; g < 2; ++g)
            gload16(Ap + (size_t)arow_[g] * K + ka + schunk * 8, As + g * 2048 + w * 512);
#pragma unroll
        for (int g = 0; g < 4; ++g)
            gload16(Bt + (size_t)(col0 + g * 32 + srow) * (2 * K) + kk + schunk * 8,
                    Bs + g * 2048 + w * 512);
        __syncthreads();
        bf16x8 a[2][2], b[2][4];
#pragma unroll
        for (int kh = 0; kh < 2; ++kh) {
#pragma unroll
            for (int m = 0; m < 2; ++m) {
                int row = wr * 32 + m * 16 + fr;
                a[kh][m] = *(const bf16x8*)(As + row * 64 + ((kh * 4 + fq) ^ (row & 7)) * 8);
            }
#pragma unroll
            for (int n = 0; n < 4; ++n) {
                int row = wc * 64 + n * 16 + fr;
                b[kh][n] = *(const bf16x8*)(Bs + row * 64 + ((kh * 4 + fq) ^ (row & 7)) * 8);
            }
        }
#pragma unroll
        for (int kh = 0; kh < 2; ++kh)
#pragma unroll
            for (int m = 0; m < 2; ++m)
#pragma unroll
                for (int n = 0; n < 4; ++n)
                    acc[m][n] = __builtin_amdgcn_mfma_f32_16x16x32_bf16(a[kh][m], b[kh][n],
                                                                        acc[m][n], 0, 0, 0);
        __syncthreads();
    }

    unsigned short* cs = Bs;
#pragma unroll
    for (int n = 0; n < 4; ++n) {
        const int col = wc * 64 + n * 16 + fr;
        const float bv = bias[col0 + col];
#pragma unroll
        for (int m = 0; m < 2; ++m) {
            const int rl = wr * 32 + m * 16 + fq * 4;
#pragma unroll
            for (int j = 0; j < 4; ++j)
                cs[(rl + j) * 128 + col] = f2bf(fmaxf(acc[m][n][j] + bv, 0.f));
        }
    }
    __syncthreads();
#pragma unroll
    for (int pass = 0; pass < 4; ++pass) {
        int idx = pass * 256 + t;
        int cr = idx >> 4;
        int cc = (idx & 15) * 8;
        int r = row0 + cr;
        if (r < N_NODES)
            *(uint4*)(out + (size_t)r * DIM + col0 + cc) = *(const uint4*)(cs + cr * 128 + cc);
    }
}

// ---------------- fused pool (sorted batch) + FC head + log_softmax ----------------

__global__ void pool_head_kernel(const unsigned short* __restrict__ h,
                                 const int* __restrict__ batch,
                                 const float* __restrict__ Wfc1, const float* __restrict__ bfc1,
                                 const float* __restrict__ Wfc2, const float* __restrict__ bfc2,
                                 float* __restrict__ out) {
    __shared__ float4 sd[4][64];
    __shared__ float row[DIM];
    __shared__ float fc1[DIM];
    __shared__ float logits[NUM_CLASSES];
    __shared__ float red[2];
    int g = blockIdx.x, t = threadIdx.x;
    int wv = t >> 6, lane = t & 63;
    int lo = 0, hi = N_NODES;
    while (lo < hi) { int m = (lo + hi) >> 1; if (batch[m] < g) lo = m + 1; else hi = m; }
    int start = lo;
    lo = 0; hi = N_NODES;
    while (lo < hi) { int m = (lo + hi) >> 1; if (batch[m] < g + 1) lo = m + 1; else hi = m; }
    int end = lo;
    float4 acc = {0.f, 0.f, 0.f, 0.f};
    for (int i = start + wv; i < end; i += 4) {
        uint2 r = *(const uint2*)(h + (size_t)i * 256 + lane * 4);
        acc.x += bf2f((unsigned short)r.x);
        acc.y += bf2f((unsigned short)(r.x >> 16));
        acc.z += bf2f((unsigned short)r.y);
        acc.w += bf2f((unsigned short)(r.y >> 16));
    }
    sd[wv][lane] = acc;
    __syncthreads();
    if (wv == 0) {
        float4 a = sd[0][lane], b = sd[1][lane], c = sd[2][lane], d = sd[3][lane];
        float4 s;
        s.x = a.x + b.x + c.x + d.x;
        s.y = a.y + b.y + c.y + d.y;
        s.z = a.z + b.z + c.z + d.z;
        s.w = a.w + b.w + c.w + d.w;
        *(float4*)(&row[lane * 4]) = s;
    }
    __syncthreads();
    float a1 = bfc1[t];
    for (int k = 0; k < DIM; ++k) a1 += row[k] * Wfc1[k * DIM + t];
    fc1[t] = fmaxf(a1, 0.f);
    __syncthreads();
    if (t < NUM_CLASSES) {
        float a = bfc2[t];
        for (int k = 0; k < DIM; ++k) a += fc1[k] * Wfc2[k * NUM_CLASSES + t];
        logits[t] = a;
    }
    __syncthreads();
    if (t == 0) {
        float mx = -INFINITY;
        for (int c2 = 0; c2 < NUM_CLASSES; ++c2) mx = fmaxf(mx, logits[c2]);
        float s = 0.f;
        for (int c2 = 0; c2 < NUM_CLASSES; ++c2) s += expf(logits[c2] - mx);
        red[0] = mx;
        red[1] = logf(s);
    }
    __syncthreads();
    if (t < NUM_CLASSES) out[g * NUM_CLASSES + t] = logits[t] - red[0] - red[1];
}

// ---------------- launch ----------------

extern "C" void kernel_launch(void* const* d_in, const int* in_sizes, int n_in,
                              void* d_out, int out_size, void* d_ws, size_t ws_size,
                              hipStream_t stream) {
    const float* x = (const float*)d_in[0];
    const int* ei = (const int*)d_in[1];
    const int* batch = (const int*)d_in[2];
    const float* ew = (const float*)d_in[3];
    const float *Wr[5], *br[5], *Wo[5];
    for (int i = 0; i < 5; ++i) {
        Wr[i] = (const float*)d_in[4 + 3 * i];
        br[i] = (const float*)d_in[5 + 3 * i];
        Wo[i] = (const float*)d_in[6 + 3 * i];
    }
    const float* Wfc1 = (const float*)d_in[19];
    const float* bfc1 = (const float*)d_in[20];
    const float* Wfc2 = (const float*)d_in[21];
    const float* bfc2 = (const float*)d_in[22];
    float* out = (float*)d_out;

    char* ws = (char*)d_ws;
    size_t off = 0;
    auto alloc = [&](size_t bytes) {
        void* p = ws + off;
        off += (bytes + 255) & ~(size_t)255;
        return p;
    };
    unsigned short* xb = (unsigned short*)alloc((size_t)N_NODES * F_IN * 2);
    unsigned short* h0 = (unsigned short*)alloc((size_t)N_NODES * DIM * 2);
    unsigned short* h1 = (unsigned short*)alloc((size_t)N_NODES * DIM * 2);
    unsigned short* aggb = (unsigned short*)alloc((size_t)N_NODES * DIM * 2);
    unsigned short* Bt[5];
    Bt[0] = (unsigned short*)alloc((size_t)2 * F_IN * DIM * 2);
    for (int i = 1; i < 5; ++i) Bt[i] = (unsigned short*)alloc((size_t)2 * DIM * DIM * 2);
    int* offs = (int*)alloc((N_NODES + 1) * 4);
    int* bcnt = (int*)alloc(NBKT * 4);
    int* bbase = (int*)alloc((NBKT + 1) * 4);
    int* gbase = (int*)alloc(NBKT * 4);
    int* blockcnt = (int*)alloc((size_t)NEB * NBKT * 4);
    uint2* edata = (uint2*)alloc((size_t)N_EDGES * 8);
    uint2* edata2 = (uint2*)alloc((size_t)N_EDGES * 8);

    const int* src = ei;
    const int* dstp = ei + N_EDGES;

    hipMemsetAsync(bcnt, 0, NBKT * 4, stream);
    bucket_hist<<<NEB, 256, 0, stream>>>(dstp, bcnt, blockcnt, N_EDGES);
    scan_bkt<<<1, 256, 0, stream>>>(bcnt, bbase, gbase);
    bucket_scatter<<<NEB, 256, 0, stream>>>(src, dstp, ew, blockcnt, gbase, edata2, N_EDGES);
    bucket_sort<<<NBKT, 256, 0, stream>>>(bbase, edata2, edata, offs);

    prep_kernel<<<NCONV + NP1 + 4 * NP2, 256, 0, stream>>>(
        x, xb, Wr[0], Wo[0], Wr[1], Wo[1], Wr[2], Wo[2], Wr[3], Wo[3], Wr[4], Wo[4], Bt[0],
        Bt[1], Bt[2], Bt[3], Bt[4]);

    const int ggrid = ((NRT64 + 7) / 8) * 16;

    // layer 1 (K = 128)
    agg_bf16<128><<<(N_NODES + 3) / 4, 256, 0, stream>>>(xb, offs, edata, aggb);
    gemm_mfma<128><<<ggrid, 256, 0, stream>>>(aggb, xb, Bt[0], br[0], h0);

    const unsigned short* hp = h0;
    unsigned short* hn = h1;
    for (int L = 1; L < 5; ++L) {
        agg_bf16<256><<<(N_NODES + 3) / 4, 256, 0, stream>>>(hp, offs, edata, aggb);
        gemm_mfma<256><<<ggrid, 256, 0, stream>>>(aggb, hp, Bt[L], br[L], hn);
        unsigned short* t2 = (unsigned short*)hp;
        hp = hn;
        hn = t2;
    }

    pool_head_kernel<<<NUM_GRAPHS, 256, 0, stream>>>(hp, batch, Wfc1, bfc1, Wfc2, bfc2, out);
}